// Round 4
// baseline (2169.883 us; speedup 1.0000x reference)
//
#include <hip/hip_runtime.h>

// LowBitMLP on MI355X (gfx950).
// R3: barrier-free direct-to-register MFMA GEMM. R2 PMC (MfmaUtil 19.6%,
// VALUBusy 16%, HBM 10%, ~1354 cyc/block-iter) showed the K-loop is
// latency-bound at the __syncthreads vmcnt(0) drain; LDS staging only gave
// 2x in-block reuse anyway (L1 covers it). So: no LDS, no barriers — each
// wave loads its A/B fragments straight to VGPRs (16B ds-free loads,
// 16 cache lines per instruction fully consumed across lanes), register
// double-buffer for 1-iter prefetch, compiler free to schedule vmcnt(N).
// XCD-aware swizzle: lin%8 -> xcd, each xcd runs 64 consecutive row-blocks
// of one B column-tile (512KB stays hot in the 4MB per-XCD L2).
//
// Memory plan:
//   d_out (64MB, scratch until GEMM2): [0,32M) x_h f16; [32M,64M) tw1 f16
//   d_ws (160MB used): [0,32M) tw2 f16; [32M,160M) h f16 (LN1+relu in place)
//   GEMM2 writes f32 directly to d_out (xh/tw1 dead); final LN in place.

#define THRESH 0.1f
#define LN_EPS 1e-5f

typedef _Float16 f16x8 __attribute__((ext_vector_type(8)));
typedef float f32x4 __attribute__((ext_vector_type(4)));

// ---------------- elementwise prep ----------------

__global__ __launch_bounds__(256) void cvt_x_f16(const float* __restrict__ x,
                                                 _Float16* __restrict__ y) {
  const long i = ((long)blockIdx.x * 256 + threadIdx.x) * 8;
  const float4 v0 = *(const float4*)(x + i);
  const float4 v1 = *(const float4*)(x + i + 4);
  const float a[8] = {v0.x, v0.y, v0.z, v0.w, v1.x, v1.y, v1.z, v1.w};
  f16x8 o;
#pragma unroll
  for (int e = 0; e < 8; ++e) o[e] = (_Float16)a[e];
  *(f16x8*)(y + i) = o;
}

__global__ __launch_bounds__(256) void quant_w(const float* __restrict__ w,
                                               _Float16* __restrict__ t) {
  const long i = ((long)blockIdx.x * 256 + threadIdx.x) * 8;
  const float4 v0 = *(const float4*)(w + i);
  const float4 v1 = *(const float4*)(w + i + 4);
  const float a[8] = {v0.x, v0.y, v0.z, v0.w, v1.x, v1.y, v1.z, v1.w};
  f16x8 o;
#pragma unroll
  for (int e = 0; e < 8; ++e) {
    const float q = (fabsf(a[e]) < THRESH) ? 0.f : (a[e] > 0.f ? 1.f : -1.f);
    o[e] = (_Float16)q;
  }
  *(f16x8*)(t + i) = o;
}

// ---------------- GEMM-BT direct: C = A(MxK) * B(NxK)^T, fused (acc+b)*s ----
// 128x128 block tile, 4 waves in 2x2, each wave 64x64 (4x4 frags of 16x16).
// A-frag: lane holds A[m=lane&15][k=(lane>>4)*8+j] => one 16B load per frag.
// No LDS, no __syncthreads in the K-loop.

template <bool OUT_F16>
__global__ __launch_bounds__(256) void gemm_bt_direct(const _Float16* __restrict__ A,
                                                      const _Float16* __restrict__ B,
                                                      void* __restrict__ C,
                                                      const float* __restrict__ bias,
                                                      const float* __restrict__ scale,
                                                      int N, int K) {
  // XCD swizzle: gridDim.y == 64 in both GEMMs (M=8192/128). gridDim.x
  // divisible by 8. xcd = lin%8 gets cols [xcd*cpx, (xcd+1)*cpx), column-major.
  const int gx = gridDim.x;
  const int lin = blockIdx.y * gx + blockIdx.x;
  const int xcd = lin & 7;
  const int s = lin >> 3;
  const int cpx = gx >> 3;
  const int bx = xcd * cpx + (s >> 6);  // s / 64  (gridDim.y == 64)
  const int by = s & 63;                // s % 64
  const long row0 = (long)by * 128;
  const long col0 = (long)bx * 128;

  const int tid = threadIdx.x, wave = tid >> 6, lane = tid & 63;
  const int l16 = lane & 15, qd = lane >> 4;
  const int wm = wave & 1, wn = wave >> 1;  // 64x64 wave sub-tile

  // Per-lane fragment base pointers (frag i at +i*16 rows).
  const _Float16* pa = A + (row0 + wm * 64 + l16) * (long)K + qd * 8;
  const _Float16* pb = B + (col0 + wn * 64 + l16) * (long)K + qd * 8;

  f32x4 acc[4][4] = {};
  f16x8 af0[4], bf0[4], af1[4], bf1[4];

  const long fstep = (long)16 * K;  // 16 rows

#define LOAD_AB(AF, BF, KK)                                             \
  {                                                                     \
    _Pragma("unroll") for (int i = 0; i < 4; ++i)                       \
        AF[i] = *(const f16x8*)(pa + i * fstep + (KK));                 \
    _Pragma("unroll") for (int j = 0; j < 4; ++j)                       \
        BF[j] = *(const f16x8*)(pb + j * fstep + (KK));                 \
  }

#define MFMA_AB(AF, BF)                                                 \
  {                                                                     \
    _Pragma("unroll") for (int i = 0; i < 4; ++i)                       \
        _Pragma("unroll") for (int j = 0; j < 4; ++j)                   \
            acc[i][j] = __builtin_amdgcn_mfma_f32_16x16x32_f16(         \
                AF[i], BF[j], acc[i][j], 0, 0, 0);                      \
  }

  const int nIter = K >> 5;  // 64 (GEMM1) / 256 (GEMM2), always even
  LOAD_AB(af0, bf0, 0)
  for (int it = 0; it < nIter; it += 2) {
    const int k1 = (it + 1) << 5;
    LOAD_AB(af1, bf1, k1)       // prefetch odd iter
    MFMA_AB(af0, bf0)           // compute even iter
    if (it + 2 < nIter) {
      const int k2 = (it + 2) << 5;
      LOAD_AB(af0, bf0, k2)     // prefetch next even iter
    }
    MFMA_AB(af1, bf1)           // compute odd iter
  }
#undef LOAD_AB
#undef MFMA_AB

  // Epilogue: C/D layout col = lane&15, row = (lane>>4)*4 + reg.
#pragma unroll
  for (int j = 0; j < 4; ++j) {
    const long c = col0 + wn * 64 + j * 16 + l16;
    const float bb = bias[c];
    const float ss = scale[c];
#pragma unroll
    for (int i = 0; i < 4; ++i) {
      const long r = row0 + wm * 64 + i * 16 + qd * 4;
#pragma unroll
      for (int reg = 0; reg < 4; ++reg) {
        const float v = (acc[i][j][reg] + bb) * ss;
        if constexpr (OUT_F16)
          ((_Float16*)C)[(r + reg) * (long)N + c] = (_Float16)v;
        else
          ((float*)C)[(r + reg) * (long)N + c] = v;
      }
    }
  }
}

// ---------------- row LayerNorm kernels ----------------

// D = 8192, f16 in/out, LN*g+b then relu, in place. One block (256 thr) per row.
__global__ __launch_bounds__(256) void ln_relu_rows_f16(_Float16* __restrict__ h,
                                                        const float* __restrict__ g,
                                                        const float* __restrict__ b) {
  const int D = 8192;
  const long base = (long)blockIdx.x * D;
  const int tid = threadIdx.x;
  f16x8 v[4];
  float sum = 0.f, sq = 0.f;
#pragma unroll
  for (int c = 0; c < 4; ++c) {
    v[c] = *(const f16x8*)&h[base + c * 2048 + tid * 8];
#pragma unroll
    for (int e = 0; e < 8; ++e) {
      const float f = (float)v[c][e];
      sum += f;
      sq += f * f;
    }
  }
#pragma unroll
  for (int off = 32; off > 0; off >>= 1) {
    sum += __shfl_down(sum, off);
    sq += __shfl_down(sq, off);
  }
  __shared__ float rs[4], rq[4];
  const int wv = tid >> 6, ln = tid & 63;
  if (ln == 0) { rs[wv] = sum; rq[wv] = sq; }
  __syncthreads();
  sum = rs[0] + rs[1] + rs[2] + rs[3];
  sq = rq[0] + rq[1] + rq[2] + rq[3];
  const float mu = sum / D;
  const float rstd = rsqrtf(sq / D - mu * mu + LN_EPS);
#pragma unroll
  for (int c = 0; c < 4; ++c) {
    const int col = c * 2048 + tid * 8;
    f16x8 o;
#pragma unroll
    for (int e = 0; e < 8; ++e) {
      const float f = ((float)v[c][e] - mu) * rstd * g[col + e] + b[col + e];
      o[e] = (_Float16)fmaxf(f, 0.f);
    }
    *(f16x8*)&h[base + col] = o;
  }
}

// D = 2048, f32, LN*g+b IN PLACE on d_out. One block (256 thr) per row;
// each block reads its whole row into registers before any write => safe.
__global__ __launch_bounds__(256) void ln_rows_f32_inplace(float* __restrict__ io,
                                                           const float* __restrict__ g,
                                                           const float* __restrict__ b) {
  const int D = 2048;
  const long base = (long)blockIdx.x * D;
  const int tid = threadIdx.x;
  const float4 v0 = *(const float4*)&io[base + tid * 8];
  const float4 v1 = *(const float4*)&io[base + tid * 8 + 4];
  const float a[8] = {v0.x, v0.y, v0.z, v0.w, v1.x, v1.y, v1.z, v1.w};
  float sum = 0.f, sq = 0.f;
#pragma unroll
  for (int e = 0; e < 8; ++e) {
    sum += a[e];
    sq += a[e] * a[e];
  }
#pragma unroll
  for (int off = 32; off > 0; off >>= 1) {
    sum += __shfl_down(sum, off);
    sq += __shfl_down(sq, off);
  }
  __shared__ float rs[4], rq[4];
  const int wv = tid >> 6, ln = tid & 63;
  if (ln == 0) { rs[wv] = sum; rq[wv] = sq; }
  __syncthreads();
  sum = rs[0] + rs[1] + rs[2] + rs[3];
  sq = rq[0] + rq[1] + rq[2] + rq[3];
  const float mu = sum / D;
  const float rstd = rsqrtf(sq / D - mu * mu + LN_EPS);
  const int col = tid * 8;
  float o[8];
#pragma unroll
  for (int e = 0; e < 8; ++e) o[e] = (a[e] - mu) * rstd * g[col + e] + b[col + e];
  *(float4*)&io[base + col] = make_float4(o[0], o[1], o[2], o[3]);
  *(float4*)&io[base + col + 4] = make_float4(o[4], o[5], o[6], o[7]);
}

// ---------------- launch ----------------

extern "C" void kernel_launch(void* const* d_in, const int* in_sizes, int n_in,
                              void* d_out, int out_size, void* d_ws, size_t ws_size,
                              hipStream_t stream) {
  const float* x    = (const float*)d_in[0];
  const float* w1   = (const float*)d_in[1];
  const float* b1   = (const float*)d_in[2];
  const float* s1   = (const float*)d_in[3];
  const float* w2   = (const float*)d_in[4];
  const float* b2   = (const float*)d_in[5];
  const float* s2   = (const float*)d_in[6];
  const float* ln1g = (const float*)d_in[7];
  const float* ln1b = (const float*)d_in[8];
  const float* outg = (const float*)d_in[9];
  const float* outb = (const float*)d_in[10];

  const int N = 8192, D_IN = 2048, D_H = 8192, D_OUT = 2048;
  const size_t MB = 1024 * 1024;
  // Scratch phase-1 buffers live in d_out (64MB); dead before GEMM2 writes it.
  char* ob = (char*)d_out;
  _Float16* xh  = (_Float16*)(ob);            // 32MB
  _Float16* tw1 = (_Float16*)(ob + 32 * MB);  // 32MB
  // Persistent-through-GEMM2 buffers in d_ws (160MB used).
  char* ws = (char*)d_ws;
  _Float16* tw2 = (_Float16*)(ws);            // 32MB
  _Float16* h   = (_Float16*)(ws + 32 * MB);  // 128MB

  // elementwise prep: each block handles 2048 elems
  cvt_x_f16<<<(N * D_IN) / 2048, 256, 0, stream>>>(x, xh);
  quant_w<<<(D_H * D_IN) / 2048, 256, 0, stream>>>(w1, tw1);
  quant_w<<<(D_OUT * D_H) / 2048, 256, 0, stream>>>(w2, tw2);

  // layer 1: h = (x @ tw1^T + b1) * s1   -> f16
  gemm_bt_direct<true><<<dim3(D_H / 128, N / 128), 256, 0, stream>>>(xh, tw1, h, b1, s1, D_H, D_IN);
  // LN + relu in place
  ln_relu_rows_f16<<<N, 256, 0, stream>>>(h, ln1g, ln1b);

  // layer 2: (h @ tw2^T + b2) * s2 -> f32, straight into d_out (xh/tw1 dead)
  gemm_bt_direct<false><<<dim3(D_OUT / 128, N / 128), 256, 0, stream>>>(h, tw2, d_out, b2, s2, D_OUT, D_H);
  // final LN in place on d_out
  ln_rows_f32_inplace<<<N, 256, 0, stream>>>((float*)d_out, outg, outb);
}